// Round 1
// baseline (1200.096 us; speedup 1.0000x reference)
//
#include <hip/hip_runtime.h>

#define N_NODES 100000
#define N_EDGES 600000
#define D 128
#define R_CHUNK 16

// ---------------------------------------------------------------------------
// Kernel 1: edge scatter-add.  32 threads per edge, each handles 4 contiguous
// floats (float4 gather, 4 scalar atomicAdds).  dst rows are random -> atomics.
// ---------------------------------------------------------------------------
__global__ void scatter_kernel(const float* __restrict__ x,
                               const int* __restrict__ ei,
                               float* __restrict__ agg) {
    int gid = blockIdx.x * blockDim.x + threadIdx.x;   // up to 19.2M, fits int
    int e = gid >> 5;
    if (e >= N_EDGES) return;
    int q = (gid & 31) * 4;                            // column offset 0..124
    int s = ei[e];                                     // src = edge_index[0][e]
    int t = ei[N_EDGES + e];                           // dst = edge_index[1][e]
    float4 v = *(const float4*)&x[(size_t)s * D + q];
    float* ap = &agg[(size_t)t * D + q];
    atomicAdd(ap + 0, v.x);
    atomicAdd(ap + 1, v.y);
    atomicAdd(ap + 2, v.z);
    atomicAdd(ap + 3, v.w);
}

// ---------------------------------------------------------------------------
// Kernel 2: fused GEMM  out[n][m] = sum_k agg[n][k]*Wrel[m][k]
//                                 + sum_k x[n][k]*Wroot[m][k] + brel[m]
// Treated as one K=256 GEMM with A = [agg_row | x_row], W2t[k][m] stacked.
// All weights in LDS (128KB, transposed so the m-axis is contiguous);
// 16 rows staged per chunk (16KB).  Total LDS 144KB -> 1 block/CU.
// Thread (mq = tid&31, rg = tid>>5) computes rows {rg, rg+8} x cols m4..m4+3.
// In-place safe when agg == out: rows are staged to LDS + sync before write.
// ---------------------------------------------------------------------------
__global__ __launch_bounds__(256, 1) void fused_gemm(
        const float* __restrict__ agg, const float* __restrict__ x,
        const float* __restrict__ Wrel, const float* __restrict__ brel,
        const float* __restrict__ Wroot, float* __restrict__ out,
        int nChunks) {
    __shared__ float W2t[256][128];        // 128 KB: W2t[k][m]
    __shared__ float rows[R_CHUNK][256];   // 16 KB:  [r][k<128]=agg, [k>=128]=x

    int tid = threadIdx.x;

    // Stage weights, transposed.  idx consecutive -> m consecutive (conflict-
    // free LDS writes); global reads are strided but only 128KB, L2-resident.
    for (int idx = tid; idx < 256 * 128; idx += 256) {
        int k = idx >> 7, m = idx & 127;
        W2t[k][m] = (k < 128) ? Wrel[m * 128 + k] : Wroot[m * 128 + (k - 128)];
    }
    __syncthreads();

    int mq = tid & 31;
    int rg = tid >> 5;      // 0..7
    int m4 = mq * 4;

    for (int chunk = blockIdx.x; chunk < nChunks; chunk += gridDim.x) {
        size_t row0 = (size_t)chunk * R_CHUNK;

        __syncthreads();    // previous iteration's readers done with `rows`
        // Stage 16 rows x 256 floats = 1024 float4s, 4 per thread, coalesced.
        for (int j = 0; j < 4; ++j) {
            int i = (tid + j * 256) * 4;
            int r = i >> 8, c = i & 255;
            float4 v;
            if (c < 128) v = *(const float4*)&agg[(row0 + r) * D + c];
            else         v = *(const float4*)&x[(row0 + r) * D + (c - 128)];
            *(float4*)&rows[r][c] = v;
        }
        __syncthreads();

        float4 acc0 = make_float4(0.f, 0.f, 0.f, 0.f);
        float4 acc1 = make_float4(0.f, 0.f, 0.f, 0.f);
        int r0 = rg, r1 = rg + 8;
#pragma unroll 8
        for (int k = 0; k < 256; ++k) {
            float4 w = *(const float4*)&W2t[k][m4];
            float a0 = rows[r0][k];
            float a1 = rows[r1][k];
            acc0.x = fmaf(a0, w.x, acc0.x);
            acc0.y = fmaf(a0, w.y, acc0.y);
            acc0.z = fmaf(a0, w.z, acc0.z);
            acc0.w = fmaf(a0, w.w, acc0.w);
            acc1.x = fmaf(a1, w.x, acc1.x);
            acc1.y = fmaf(a1, w.y, acc1.y);
            acc1.z = fmaf(a1, w.z, acc1.z);
            acc1.w = fmaf(a1, w.w, acc1.w);
        }

        float4 b = *(const float4*)&brel[m4];
        float4 o0 = make_float4(acc0.x + b.x, acc0.y + b.y,
                                acc0.z + b.z, acc0.w + b.w);
        float4 o1 = make_float4(acc1.x + b.x, acc1.y + b.y,
                                acc1.z + b.z, acc1.w + b.w);
        *(float4*)&out[(row0 + r0) * D + m4] = o0;
        *(float4*)&out[(row0 + r1) * D + m4] = o1;
    }
}

extern "C" void kernel_launch(void* const* d_in, const int* in_sizes, int n_in,
                              void* d_out, int out_size, void* d_ws, size_t ws_size,
                              hipStream_t stream) {
    const float* x     = (const float*)d_in[0];
    const int*   ei    = (const int*)d_in[1];
    const float* Wrel  = (const float*)d_in[2];
    const float* brel  = (const float*)d_in[3];
    const float* Wroot = (const float*)d_in[4];
    float* out = (float*)d_out;

    size_t aggBytes = (size_t)N_NODES * D * sizeof(float);
    float* agg = (ws_size >= aggBytes) ? (float*)d_ws : out;

    // Zero the aggregation buffer (graph-capturable).
    hipMemsetAsync(agg, 0, aggBytes, stream);

    // Edge scatter: 32 threads/edge.
    int scatterThreads = N_EDGES * 32;
    scatter_kernel<<<(scatterThreads + 255) / 256, 256, 0, stream>>>(x, ei, agg);

    // Fused GEMM + bias.
    fused_gemm<<<256, 256, 0, stream>>>(agg, x, Wrel, brel, Wroot, out,
                                        N_NODES / R_CHUNK);
}

// Round 2
// 549.222 us; speedup vs baseline: 2.1851x; 2.1851x over previous
//
#include <hip/hip_runtime.h>

#define N_NODES 100000
#define N_EDGES 600000
#define D 128
#define R_CHUNK 16
#define SCAN_THREADS 1024
#define RUN 98   // ceil((N_NODES+1)/SCAN_THREADS)

// ---------------------------------------------------------------------------
// Counting-sort pipeline (no float atomics):
//   hist -> scan (offsets + cursor) -> scatter_idx (srcSorted) -> seg_sum
// ---------------------------------------------------------------------------
__global__ void hist_kernel(const int* __restrict__ ei, int* __restrict__ counts) {
    int e = blockIdx.x * blockDim.x + threadIdx.x;
    if (e >= N_EDGES) return;
    atomicAdd(&counts[ei[N_EDGES + e]], 1);
}

// Single-block exclusive scan: thread t serially sums counts[t*RUN .. ),
// LDS Hillis-Steele over 1024 partials, then serial write-back.
__global__ __launch_bounds__(SCAN_THREADS, 1) void scan_kernel(
        const int* __restrict__ counts, int* __restrict__ offsets,
        int* __restrict__ cursor) {
    __shared__ int part[SCAN_THREADS];
    int t = threadIdx.x;
    int base = t * RUN;
    int s = 0;
    for (int i = 0; i < RUN; ++i) {
        int idx = base + i;
        if (idx < N_NODES) s += counts[idx];
    }
    part[t] = s;
    __syncthreads();
    for (int off = 1; off < SCAN_THREADS; off <<= 1) {
        int v = (t >= off) ? part[t - off] : 0;
        __syncthreads();
        part[t] += v;
        __syncthreads();
    }
    int run = (t > 0) ? part[t - 1] : 0;   // exclusive prefix of this run
    for (int i = 0; i < RUN; ++i) {
        int idx = base + i;
        if (idx <= N_NODES) {
            offsets[idx] = run;
            if (idx < N_NODES) {
                cursor[idx] = run;
                run += counts[idx];
            }
        }
    }
}

__global__ void scatter_idx_kernel(const int* __restrict__ ei,
                                   int* __restrict__ cursor,
                                   int* __restrict__ srcSorted) {
    int e = blockIdx.x * blockDim.x + threadIdx.x;
    if (e >= N_EDGES) return;
    int s = ei[e];
    int t = ei[N_EDGES + e];
    int pos = atomicAdd(&cursor[t], 1);
    srcSorted[pos] = s;
}

// One wave per node; lane holds 2 f32 columns (float2, 512B/wave/edge).
// x (51.2 MB) is Infinity-Cache resident -> gathers hit L3, agg written once.
__global__ void seg_sum_kernel(const float* __restrict__ x,
                               const int* __restrict__ offsets,
                               const int* __restrict__ srcSorted,
                               float* __restrict__ agg) {
    int wid = (blockIdx.x * blockDim.x + threadIdx.x) >> 6;
    if (wid >= N_NODES) return;
    int lane = threadIdx.x & 63;
    int c = lane * 2;
    int beg = offsets[wid], end = offsets[wid + 1];
    float2 acc = make_float2(0.f, 0.f);
    int p = beg;
    for (; p + 1 < end; p += 2) {           // 2-edge unroll for load ILP
        int s0 = srcSorted[p], s1 = srcSorted[p + 1];
        float2 v0 = *(const float2*)&x[(size_t)s0 * D + c];
        float2 v1 = *(const float2*)&x[(size_t)s1 * D + c];
        acc.x += v0.x + v1.x;
        acc.y += v0.y + v1.y;
    }
    if (p < end) {
        int s0 = srcSorted[p];
        float2 v0 = *(const float2*)&x[(size_t)s0 * D + c];
        acc.x += v0.x;
        acc.y += v0.y;
    }
    *(float2*)&agg[(size_t)wid * D + c] = acc;
}

// ---------------------------------------------------------------------------
// Fallback scatter (atomic f32) if workspace is too small for sort buffers.
// ---------------------------------------------------------------------------
__global__ void scatter_kernel(const float* __restrict__ x,
                               const int* __restrict__ ei,
                               float* __restrict__ agg) {
    int gid = blockIdx.x * blockDim.x + threadIdx.x;
    int e = gid >> 5;
    if (e >= N_EDGES) return;
    int q = (gid & 31) * 4;
    int s = ei[e];
    int t = ei[N_EDGES + e];
    float4 v = *(const float4*)&x[(size_t)s * D + q];
    float* ap = &agg[(size_t)t * D + q];
    atomicAdd(ap + 0, v.x);
    atomicAdd(ap + 1, v.y);
    atomicAdd(ap + 2, v.z);
    atomicAdd(ap + 3, v.w);
}

// ---------------------------------------------------------------------------
// Fused GEMM  out[n][m] = sum_k agg[n][k]*Wrel[m][k]
//                       + sum_k x[n][k]*Wroot[m][k] + brel[m]
// K=256 with A = [agg_row | x_row]; weights (transposed) fully in LDS.
// In-place safe when agg == out (rows staged to LDS before write).
// ---------------------------------------------------------------------------
__global__ __launch_bounds__(256, 1) void fused_gemm(
        const float* __restrict__ agg, const float* __restrict__ x,
        const float* __restrict__ Wrel, const float* __restrict__ brel,
        const float* __restrict__ Wroot, float* __restrict__ out,
        int nChunks) {
    __shared__ float W2t[256][128];        // 128 KB: W2t[k][m]
    __shared__ float rows[R_CHUNK][256];   // 16 KB

    int tid = threadIdx.x;
    for (int idx = tid; idx < 256 * 128; idx += 256) {
        int k = idx >> 7, m = idx & 127;
        W2t[k][m] = (k < 128) ? Wrel[m * 128 + k] : Wroot[m * 128 + (k - 128)];
    }
    __syncthreads();

    int mq = tid & 31;
    int rg = tid >> 5;
    int m4 = mq * 4;

    for (int chunk = blockIdx.x; chunk < nChunks; chunk += gridDim.x) {
        size_t row0 = (size_t)chunk * R_CHUNK;

        __syncthreads();
        for (int j = 0; j < 4; ++j) {
            int i = (tid + j * 256) * 4;
            int r = i >> 8, c = i & 255;
            float4 v;
            if (c < 128) v = *(const float4*)&agg[(row0 + r) * D + c];
            else         v = *(const float4*)&x[(row0 + r) * D + (c - 128)];
            *(float4*)&rows[r][c] = v;
        }
        __syncthreads();

        float4 acc0 = make_float4(0.f, 0.f, 0.f, 0.f);
        float4 acc1 = make_float4(0.f, 0.f, 0.f, 0.f);
        int r0 = rg, r1 = rg + 8;
#pragma unroll 8
        for (int k = 0; k < 256; ++k) {
            float4 w = *(const float4*)&W2t[k][m4];
            float a0 = rows[r0][k];
            float a1 = rows[r1][k];
            acc0.x = fmaf(a0, w.x, acc0.x);
            acc0.y = fmaf(a0, w.y, acc0.y);
            acc0.z = fmaf(a0, w.z, acc0.z);
            acc0.w = fmaf(a0, w.w, acc0.w);
            acc1.x = fmaf(a1, w.x, acc1.x);
            acc1.y = fmaf(a1, w.y, acc1.y);
            acc1.z = fmaf(a1, w.z, acc1.z);
            acc1.w = fmaf(a1, w.w, acc1.w);
        }

        float4 b = *(const float4*)&brel[m4];
        *(float4*)&out[(row0 + r0) * D + m4] =
            make_float4(acc0.x + b.x, acc0.y + b.y, acc0.z + b.z, acc0.w + b.w);
        *(float4*)&out[(row0 + r1) * D + m4] =
            make_float4(acc1.x + b.x, acc1.y + b.y, acc1.z + b.z, acc1.w + b.w);
    }
}

extern "C" void kernel_launch(void* const* d_in, const int* in_sizes, int n_in,
                              void* d_out, int out_size, void* d_ws, size_t ws_size,
                              hipStream_t stream) {
    const float* x     = (const float*)d_in[0];
    const int*   ei    = (const int*)d_in[1];
    const float* Wrel  = (const float*)d_in[2];
    const float* brel  = (const float*)d_in[3];
    const float* Wroot = (const float*)d_in[4];
    float* out = (float*)d_out;

    const size_t aggBytes    = (size_t)N_NODES * D * sizeof(float);   // 51.2 MB
    const size_t offBytes    = (size_t)(N_NODES + 1) * sizeof(int);
    const size_t curBytes    = (size_t)N_NODES * sizeof(int);
    const size_t srcBytes    = (size_t)N_EDGES * sizeof(int);
    const size_t cntBytes    = (size_t)N_NODES * sizeof(int);
    auto align16 = [](size_t v) { return (v + 15) & ~(size_t)15; };

    size_t o_agg = 0;
    size_t o_off = align16(o_agg + aggBytes);
    size_t o_cur = align16(o_off + offBytes);
    size_t o_src = align16(o_cur + curBytes);
    size_t o_cnt = align16(o_src + srcBytes);
    size_t total = o_cnt + cntBytes;

    if (ws_size >= total) {
        char* ws = (char*)d_ws;
        float* agg      = (float*)(ws + o_agg);
        int*   offsets  = (int*)(ws + o_off);
        int*   cursor   = (int*)(ws + o_cur);
        int*   srcSorted= (int*)(ws + o_src);
        int*   counts   = (int*)(ws + o_cnt);

        hipMemsetAsync(counts, 0, cntBytes, stream);
        hist_kernel<<<(N_EDGES + 255) / 256, 256, 0, stream>>>(ei, counts);
        scan_kernel<<<1, SCAN_THREADS, 0, stream>>>(counts, offsets, cursor);
        scatter_idx_kernel<<<(N_EDGES + 255) / 256, 256, 0, stream>>>(ei, cursor, srcSorted);
        seg_sum_kernel<<<(N_NODES * 64 + 255) / 256, 256, 0, stream>>>(x, offsets, srcSorted, agg);
        fused_gemm<<<256, 256, 0, stream>>>(agg, x, Wrel, brel, Wroot, out,
                                            N_NODES / R_CHUNK);
    } else {
        // Fallback: atomic scatter (round-1 path).
        float* agg = (ws_size >= aggBytes) ? (float*)d_ws : out;
        hipMemsetAsync(agg, 0, aggBytes, stream);
        scatter_kernel<<<(N_EDGES * 32 + 255) / 256, 256, 0, stream>>>(x, ei, agg);
        fused_gemm<<<256, 256, 0, stream>>>(agg, x, Wrel, brel, Wroot, out,
                                            N_NODES / R_CHUNK);
    }
}

// Round 3
// 298.081 us; speedup vs baseline: 4.0261x; 1.8425x over previous
//
#include <hip/hip_runtime.h>

#define N_NODES 100000
#define N_EDGES 600000
#define D 128
#define R_CHUNK 16
#define SCAN_TILE 1024
#define NBLK 98   // ceil(N_NODES / SCAN_TILE)

// ---------------------------------------------------------------------------
// Counting-sort pipeline (no float atomics):
//   hist -> 3-phase scan (offsets + cursor) -> scatter_idx -> seg_sum
// ---------------------------------------------------------------------------
__global__ void hist_kernel(const int* __restrict__ ei, int* __restrict__ counts) {
    int e = blockIdx.x * blockDim.x + threadIdx.x;
    if (e >= N_EDGES) return;
    atomicAdd(&counts[ei[N_EDGES + e]], 1);
}

// Phase A: per-tile sums (coalesced read, LDS tree reduce).
__global__ __launch_bounds__(SCAN_TILE) void tile_sum_kernel(
        const int* __restrict__ counts, int* __restrict__ blockSums) {
    __shared__ int sh[SCAN_TILE];
    int t = threadIdx.x;
    int gid = blockIdx.x * SCAN_TILE + t;
    sh[t] = (gid < N_NODES) ? counts[gid] : 0;
    __syncthreads();
    for (int off = SCAN_TILE / 2; off > 0; off >>= 1) {
        if (t < off) sh[t] += sh[t + off];
        __syncthreads();
    }
    if (t == 0) blockSums[blockIdx.x] = sh[0];
}

// Phase B: exclusive scan of the 98 tile sums (one tiny block).
__global__ void scan_blocks_kernel(const int* __restrict__ blockSums,
                                   int* __restrict__ blockOff) {
    __shared__ int sh[128];
    int t = threadIdx.x;
    int v = (t < NBLK) ? blockSums[t] : 0;
    sh[t] = v;
    __syncthreads();
    for (int off = 1; off < 128; off <<= 1) {
        int u = (t >= off) ? sh[t - off] : 0;
        __syncthreads();
        sh[t] += u;
        __syncthreads();
    }
    if (t < NBLK) blockOff[t] = sh[t] - v;   // exclusive
}

// Phase C: intra-tile exclusive scan + tile offset -> offsets, cursor.
__global__ __launch_bounds__(SCAN_TILE) void scan_tile_kernel(
        const int* __restrict__ counts, const int* __restrict__ blockOff,
        int* __restrict__ offsets, int* __restrict__ cursor) {
    __shared__ int sh[SCAN_TILE];
    int t = threadIdx.x;
    int gid = blockIdx.x * SCAN_TILE + t;
    int v = (gid < N_NODES) ? counts[gid] : 0;
    sh[t] = v;
    __syncthreads();
    for (int off = 1; off < SCAN_TILE; off <<= 1) {
        int u = (t >= off) ? sh[t - off] : 0;
        __syncthreads();
        sh[t] += u;
        __syncthreads();
    }
    int excl = sh[t] - v + blockOff[blockIdx.x];
    if (gid < N_NODES) {
        offsets[gid] = excl;
        cursor[gid] = excl;
    }
    if (gid == N_NODES - 1) offsets[N_NODES] = excl + v;  // == N_EDGES
}

__global__ void scatter_idx_kernel(const int* __restrict__ ei,
                                   int* __restrict__ cursor,
                                   int* __restrict__ srcSorted) {
    int e = blockIdx.x * blockDim.x + threadIdx.x;
    if (e >= N_EDGES) return;
    int s = ei[e];
    int t = ei[N_EDGES + e];
    int pos = atomicAdd(&cursor[t], 1);
    srcSorted[pos] = s;
}

// One wave per node; lane holds 2 f32 columns.  x (51.2 MB) is L3-resident.
__global__ void seg_sum_kernel(const float* __restrict__ x,
                               const int* __restrict__ offsets,
                               const int* __restrict__ srcSorted,
                               float* __restrict__ agg) {
    int wid = (blockIdx.x * blockDim.x + threadIdx.x) >> 6;
    if (wid >= N_NODES) return;
    int lane = threadIdx.x & 63;
    int c = lane * 2;
    int beg = offsets[wid], end = offsets[wid + 1];
    float2 acc = make_float2(0.f, 0.f);
    int p = beg;
    for (; p + 1 < end; p += 2) {
        int s0 = srcSorted[p], s1 = srcSorted[p + 1];
        float2 v0 = *(const float2*)&x[(size_t)s0 * D + c];
        float2 v1 = *(const float2*)&x[(size_t)s1 * D + c];
        acc.x += v0.x + v1.x;
        acc.y += v0.y + v1.y;
    }
    if (p < end) {
        int s0 = srcSorted[p];
        float2 v0 = *(const float2*)&x[(size_t)s0 * D + c];
        acc.x += v0.x;
        acc.y += v0.y;
    }
    *(float2*)&agg[(size_t)wid * D + c] = acc;
}

// ---------------------------------------------------------------------------
// Fallback scatter (atomic f32) if workspace is too small for sort buffers.
// ---------------------------------------------------------------------------
__global__ void scatter_kernel(const float* __restrict__ x,
                               const int* __restrict__ ei,
                               float* __restrict__ agg) {
    int gid = blockIdx.x * blockDim.x + threadIdx.x;
    int e = gid >> 5;
    if (e >= N_EDGES) return;
    int q = (gid & 31) * 4;
    int s = ei[e];
    int t = ei[N_EDGES + e];
    float4 v = *(const float4*)&x[(size_t)s * D + q];
    float* ap = &agg[(size_t)t * D + q];
    atomicAdd(ap + 0, v.x);
    atomicAdd(ap + 1, v.y);
    atomicAdd(ap + 2, v.z);
    atomicAdd(ap + 3, v.w);
}

// ---------------------------------------------------------------------------
// Fused GEMM  out[n][m] = sum_k agg[n][k]*Wrel[m][k]
//                       + sum_k x[n][k]*Wroot[m][k] + brel[m]
// K=256 with A = [agg_row | x_row]; weights (transposed) fully in LDS.
// In-place safe when agg == out (rows staged to LDS before write).
// ---------------------------------------------------------------------------
__global__ __launch_bounds__(256, 1) void fused_gemm(
        const float* __restrict__ agg, const float* __restrict__ x,
        const float* __restrict__ Wrel, const float* __restrict__ brel,
        const float* __restrict__ Wroot, float* __restrict__ out,
        int nChunks) {
    __shared__ float W2t[256][128];        // 128 KB: W2t[k][m]
    __shared__ float rows[R_CHUNK][256];   // 16 KB

    int tid = threadIdx.x;
    for (int idx = tid; idx < 256 * 128; idx += 256) {
        int k = idx >> 7, m = idx & 127;
        W2t[k][m] = (k < 128) ? Wrel[m * 128 + k] : Wroot[m * 128 + (k - 128)];
    }
    __syncthreads();

    int mq = tid & 31;
    int rg = tid >> 5;
    int m4 = mq * 4;

    for (int chunk = blockIdx.x; chunk < nChunks; chunk += gridDim.x) {
        size_t row0 = (size_t)chunk * R_CHUNK;

        __syncthreads();
        for (int j = 0; j < 4; ++j) {
            int i = (tid + j * 256) * 4;
            int r = i >> 8, c = i & 255;
            float4 v;
            if (c < 128) v = *(const float4*)&agg[(row0 + r) * D + c];
            else         v = *(const float4*)&x[(row0 + r) * D + (c - 128)];
            *(float4*)&rows[r][c] = v;
        }
        __syncthreads();

        float4 acc0 = make_float4(0.f, 0.f, 0.f, 0.f);
        float4 acc1 = make_float4(0.f, 0.f, 0.f, 0.f);
        int r0 = rg, r1 = rg + 8;
#pragma unroll 8
        for (int k = 0; k < 256; ++k) {
            float4 w = *(const float4*)&W2t[k][m4];
            float a0 = rows[r0][k];
            float a1 = rows[r1][k];
            acc0.x = fmaf(a0, w.x, acc0.x);
            acc0.y = fmaf(a0, w.y, acc0.y);
            acc0.z = fmaf(a0, w.z, acc0.z);
            acc0.w = fmaf(a0, w.w, acc0.w);
            acc1.x = fmaf(a1, w.x, acc1.x);
            acc1.y = fmaf(a1, w.y, acc1.y);
            acc1.z = fmaf(a1, w.z, acc1.z);
            acc1.w = fmaf(a1, w.w, acc1.w);
        }

        float4 b = *(const float4*)&brel[m4];
        *(float4*)&out[(row0 + r0) * D + m4] =
            make_float4(acc0.x + b.x, acc0.y + b.y, acc0.z + b.z, acc0.w + b.w);
        *(float4*)&out[(row0 + r1) * D + m4] =
            make_float4(acc1.x + b.x, acc1.y + b.y, acc1.z + b.z, acc1.w + b.w);
    }
}

extern "C" void kernel_launch(void* const* d_in, const int* in_sizes, int n_in,
                              void* d_out, int out_size, void* d_ws, size_t ws_size,
                              hipStream_t stream) {
    const float* x     = (const float*)d_in[0];
    const int*   ei    = (const int*)d_in[1];
    const float* Wrel  = (const float*)d_in[2];
    const float* brel  = (const float*)d_in[3];
    const float* Wroot = (const float*)d_in[4];
    float* out = (float*)d_out;

    const size_t aggBytes = (size_t)N_NODES * D * sizeof(float);   // 51.2 MB
    const size_t offBytes = (size_t)(N_NODES + 1) * sizeof(int);
    const size_t curBytes = (size_t)N_NODES * sizeof(int);
    const size_t srcBytes = (size_t)N_EDGES * sizeof(int);
    const size_t cntBytes = (size_t)N_NODES * sizeof(int);
    const size_t blkBytes = (size_t)NBLK * sizeof(int);
    auto align16 = [](size_t v) { return (v + 15) & ~(size_t)15; };

    size_t o_agg = 0;
    size_t o_off = align16(o_agg + aggBytes);
    size_t o_cur = align16(o_off + offBytes);
    size_t o_src = align16(o_cur + curBytes);
    size_t o_cnt = align16(o_src + srcBytes);
    size_t o_bs  = align16(o_cnt + cntBytes);
    size_t o_bo  = align16(o_bs + blkBytes);
    size_t total = o_bo + blkBytes;

    if (ws_size >= total) {
        char* ws = (char*)d_ws;
        float* agg       = (float*)(ws + o_agg);
        int*   offsets   = (int*)(ws + o_off);
        int*   cursor    = (int*)(ws + o_cur);
        int*   srcSorted = (int*)(ws + o_src);
        int*   counts    = (int*)(ws + o_cnt);
        int*   blockSums = (int*)(ws + o_bs);
        int*   blockOff  = (int*)(ws + o_bo);

        hipMemsetAsync(counts, 0, cntBytes, stream);
        hist_kernel<<<(N_EDGES + 255) / 256, 256, 0, stream>>>(ei, counts);
        tile_sum_kernel<<<NBLK, SCAN_TILE, 0, stream>>>(counts, blockSums);
        scan_blocks_kernel<<<1, 128, 0, stream>>>(blockSums, blockOff);
        scan_tile_kernel<<<NBLK, SCAN_TILE, 0, stream>>>(counts, blockOff, offsets, cursor);
        scatter_idx_kernel<<<(N_EDGES + 255) / 256, 256, 0, stream>>>(ei, cursor, srcSorted);
        seg_sum_kernel<<<(N_NODES * 64 + 255) / 256, 256, 0, stream>>>(x, offsets, srcSorted, agg);
        fused_gemm<<<256, 256, 0, stream>>>(agg, x, Wrel, brel, Wroot, out,
                                            N_NODES / R_CHUNK);
    } else {
        float* agg = (ws_size >= aggBytes) ? (float*)d_ws : out;
        hipMemsetAsync(agg, 0, aggBytes, stream);
        scatter_kernel<<<(N_EDGES * 32 + 255) / 256, 256, 0, stream>>>(x, ei, agg);
        fused_gemm<<<256, 256, 0, stream>>>(agg, x, Wrel, brel, Wroot, out,
                                            N_NODES / R_CHUNK);
    }
}

// Round 4
// 174.987 us; speedup vs baseline: 6.8582x; 1.7034x over previous
//
#include <hip/hip_runtime.h>

#define N_NODES 100000
#define N_EDGES 600000
#define D 128
#define K2 256          // stacked K = [agg | x]
#define SCAN_TILE 1024
#define NBLK 98         // ceil(N_NODES / SCAN_TILE)

typedef __attribute__((ext_vector_type(8))) short short8;
typedef __attribute__((ext_vector_type(4))) float f32x4;

__device__ __forceinline__ unsigned short f2bf(float f) {
    union { float f; unsigned u; } v; v.f = f;
    unsigned u = v.u;
    u += 0x7FFFu + ((u >> 16) & 1u);     // round-to-nearest-even
    return (unsigned short)(u >> 16);
}

// ---------------------------------------------------------------------------
// Counting sort: hist -> 3-phase scan -> scatter_idx
// ---------------------------------------------------------------------------
__global__ void hist_kernel(const int* __restrict__ ei, int* __restrict__ counts) {
    int e = blockIdx.x * blockDim.x + threadIdx.x;
    if (e >= N_EDGES) return;
    atomicAdd(&counts[ei[N_EDGES + e]], 1);
}

__global__ __launch_bounds__(SCAN_TILE) void tile_sum_kernel(
        const int* __restrict__ counts, int* __restrict__ blockSums) {
    __shared__ int sh[SCAN_TILE];
    int t = threadIdx.x;
    int gid = blockIdx.x * SCAN_TILE + t;
    sh[t] = (gid < N_NODES) ? counts[gid] : 0;
    __syncthreads();
    for (int off = SCAN_TILE / 2; off > 0; off >>= 1) {
        if (t < off) sh[t] += sh[t + off];
        __syncthreads();
    }
    if (t == 0) blockSums[blockIdx.x] = sh[0];
}

__global__ void scan_blocks_kernel(const int* __restrict__ blockSums,
                                   int* __restrict__ blockOff) {
    __shared__ int sh[128];
    int t = threadIdx.x;
    int v = (t < NBLK) ? blockSums[t] : 0;
    sh[t] = v;
    __syncthreads();
    for (int off = 1; off < 128; off <<= 1) {
        int u = (t >= off) ? sh[t - off] : 0;
        __syncthreads();
        sh[t] += u;
        __syncthreads();
    }
    if (t < NBLK) blockOff[t] = sh[t] - v;
}

__global__ __launch_bounds__(SCAN_TILE) void scan_tile_kernel(
        const int* __restrict__ counts, const int* __restrict__ blockOff,
        int* __restrict__ offsets, int* __restrict__ cursor) {
    __shared__ int sh[SCAN_TILE];
    int t = threadIdx.x;
    int gid = blockIdx.x * SCAN_TILE + t;
    int v = (gid < N_NODES) ? counts[gid] : 0;
    sh[t] = v;
    __syncthreads();
    for (int off = 1; off < SCAN_TILE; off <<= 1) {
        int u = (t >= off) ? sh[t - off] : 0;
        __syncthreads();
        sh[t] += u;
        __syncthreads();
    }
    int excl = sh[t] - v + blockOff[blockIdx.x];
    if (gid < N_NODES) {
        offsets[gid] = excl;
        cursor[gid] = excl;
    }
    if (gid == N_NODES - 1) offsets[N_NODES] = excl + v;
}

__global__ void scatter_idx_kernel(const int* __restrict__ ei,
                                   int* __restrict__ cursor,
                                   int* __restrict__ srcSorted) {
    int e = blockIdx.x * blockDim.x + threadIdx.x;
    if (e >= N_EDGES) return;
    int s = ei[e];
    int t = ei[N_EDGES + e];
    int pos = atomicAdd(&cursor[t], 1);
    srcSorted[pos] = s;
}

// ---------------------------------------------------------------------------
// seg_sum: one wave per node, lane = 2 cols; writes bf16 into Amat[:,0:128).
// ---------------------------------------------------------------------------
__global__ void seg_sum_kernel(const float* __restrict__ x,
                               const int* __restrict__ offsets,
                               const int* __restrict__ srcSorted,
                               unsigned short* __restrict__ Amat) {
    int wid = (blockIdx.x * blockDim.x + threadIdx.x) >> 6;
    if (wid >= N_NODES) return;
    int lane = threadIdx.x & 63;
    int c = lane * 2;
    int beg = offsets[wid], end = offsets[wid + 1];
    float2 acc = make_float2(0.f, 0.f);
    int p = beg;
    for (; p + 1 < end; p += 2) {
        int s0 = srcSorted[p], s1 = srcSorted[p + 1];
        float2 v0 = *(const float2*)&x[(size_t)s0 * D + c];
        float2 v1 = *(const float2*)&x[(size_t)s1 * D + c];
        acc.x += v0.x + v1.x;
        acc.y += v0.y + v1.y;
    }
    if (p < end) {
        int s0 = srcSorted[p];
        float2 v0 = *(const float2*)&x[(size_t)s0 * D + c];
        acc.x += v0.x;
        acc.y += v0.y;
    }
    unsigned pack = (unsigned)f2bf(acc.x) | ((unsigned)f2bf(acc.y) << 16);
    *(unsigned*)&Amat[(size_t)wid * K2 + c] = pack;
}

// ---------------------------------------------------------------------------
// convert_x: x fp32 -> Amat[:,128:256) bf16.  1 thread = 8 contiguous elems.
// ---------------------------------------------------------------------------
__global__ void convert_x_kernel(const float* __restrict__ x,
                                 unsigned short* __restrict__ Amat) {
    int t = blockIdx.x * blockDim.x + threadIdx.x;
    if (t >= N_NODES * 16) return;
    int n = t >> 4, c8 = (t & 15) * 8;
    const float4* p = (const float4*)&x[(size_t)n * D + c8];
    float4 v0 = p[0], v1 = p[1];
    uint4 o;
    o.x = (unsigned)f2bf(v0.x) | ((unsigned)f2bf(v0.y) << 16);
    o.y = (unsigned)f2bf(v0.z) | ((unsigned)f2bf(v0.w) << 16);
    o.z = (unsigned)f2bf(v1.x) | ((unsigned)f2bf(v1.y) << 16);
    o.w = (unsigned)f2bf(v1.z) | ((unsigned)f2bf(v1.w) << 16);
    *(uint4*)&Amat[(size_t)n * K2 + 128 + c8] = o;
}

// ---------------------------------------------------------------------------
// wprep: pack stacked weights [Wrel;Wroot] into MFMA B-fragment order, bf16.
// slot = (ct*8 + ks)*64 + lane; lane holds B[k0..k0+8)[m], m = ct*16+(lane&15),
// k0 = ks*32 + (lane>>4)*8.  W stored [out=m][in=k] -> 8 contiguous fp32.
// ---------------------------------------------------------------------------
__global__ void wprep_kernel(const float* __restrict__ Wrel,
                             const float* __restrict__ Wroot,
                             unsigned short* __restrict__ Wfrag) {
    int slot = blockIdx.x * blockDim.x + threadIdx.x;
    if (slot >= 4096) return;
    int lane = slot & 63;
    int ks = (slot >> 6) & 7;
    int ct = slot >> 9;
    int m = ct * 16 + (lane & 15);
    int k = ks * 32 + (lane >> 4) * 8;
    const float* src = (k < 128) ? &Wrel[(size_t)m * 128 + k]
                                 : &Wroot[(size_t)m * 128 + (k - 128)];
    uint4 o;
    o.x = (unsigned)f2bf(src[0]) | ((unsigned)f2bf(src[1]) << 16);
    o.y = (unsigned)f2bf(src[2]) | ((unsigned)f2bf(src[3]) << 16);
    o.z = (unsigned)f2bf(src[4]) | ((unsigned)f2bf(src[5]) << 16);
    o.w = (unsigned)f2bf(src[6]) | ((unsigned)f2bf(src[7]) << 16);
    *(uint4*)&Wfrag[(size_t)slot * 8] = o;
}

// ---------------------------------------------------------------------------
// gemm_mfma: out[n][m] = Amat[n][:] (bf16, K=256) . Wfrag + brel[m], fp32 out.
// 4 waves/block, 32 rows/wave (2 row-tiles x 8 col-tiles), K-loop of 8.
// B fragments from LDS (conflict-free ds_read_b128); A frags direct from
// global (L2/L3-resident), prefetched one K-step ahead.
// ---------------------------------------------------------------------------
__global__ __launch_bounds__(256, 2) void gemm_mfma(
        const unsigned short* __restrict__ Amat,
        const unsigned short* __restrict__ Wfrag,
        const float* __restrict__ brel,
        float* __restrict__ out) {
    __shared__ short8 Wlds[4096];   // 64 KB
    int tid = threadIdx.x;
    for (int i = tid; i < 4096; i += 256)
        Wlds[i] = *(const short8*)&Wfrag[(size_t)i * 8];
    __syncthreads();

    int lane = tid & 63;
    int w = tid >> 6;
    int n16 = lane & 15, kg = lane >> 4;
    long row0 = (long)blockIdx.x * 128 + w * 32;

    long r0 = row0 + n16;
    long r1 = row0 + 16 + n16;
    long cr0 = (r0 < N_NODES) ? r0 : (N_NODES - 1);
    long cr1 = (r1 < N_NODES) ? r1 : (N_NODES - 1);
    const short8* a0p = (const short8*)(Amat + cr0 * K2 + kg * 8);
    const short8* a1p = (const short8*)(Amat + cr1 * K2 + kg * 8);

    f32x4 acc[2][8];
#pragma unroll
    for (int h = 0; h < 2; ++h)
#pragma unroll
        for (int ct = 0; ct < 8; ++ct)
            acc[h][ct] = (f32x4){0.f, 0.f, 0.f, 0.f};

    short8 a0 = a0p[0], a1 = a1p[0];
#pragma unroll
    for (int ks = 0; ks < 8; ++ks) {
        short8 na0, na1;
        if (ks < 7) {                 // prefetch next K-step (32 shorts = 4 frags)
            na0 = a0p[(ks + 1) * 4];
            na1 = a1p[(ks + 1) * 4];
        }
#pragma unroll
        for (int ct = 0; ct < 8; ++ct) {
            short8 b = Wlds[(ct * 8 + ks) * 64 + lane];
            acc[0][ct] = __builtin_amdgcn_mfma_f32_16x16x32_bf16(a0, b, acc[0][ct], 0, 0, 0);
            acc[1][ct] = __builtin_amdgcn_mfma_f32_16x16x32_bf16(a1, b, acc[1][ct], 0, 0, 0);
        }
        a0 = na0; a1 = na1;
    }

    // D layout (measured m89): col = lane&15, row = 4*(lane>>4) + reg.
#pragma unroll
    for (int h = 0; h < 2; ++h) {
        long rb = row0 + h * 16 + 4 * kg;
#pragma unroll
        for (int ct = 0; ct < 8; ++ct) {
            float bias = brel[ct * 16 + n16];
#pragma unroll
            for (int r = 0; r < 4; ++r) {
                long row = rb + r;
                if (row < N_NODES)
                    out[row * 128 + ct * 16 + n16] = acc[h][ct][r] + bias;
            }
        }
    }
}

// ---------------------------------------------------------------------------
// Fallback (ws too small): atomic scatter + fp32 GEMM (round-1 path).
// ---------------------------------------------------------------------------
__global__ void scatter_kernel(const float* __restrict__ x,
                               const int* __restrict__ ei,
                               float* __restrict__ agg) {
    int gid = blockIdx.x * blockDim.x + threadIdx.x;
    int e = gid >> 5;
    if (e >= N_EDGES) return;
    int q = (gid & 31) * 4;
    int s = ei[e];
    int t = ei[N_EDGES + e];
    float4 v = *(const float4*)&x[(size_t)s * D + q];
    float* ap = &agg[(size_t)t * D + q];
    atomicAdd(ap + 0, v.x);
    atomicAdd(ap + 1, v.y);
    atomicAdd(ap + 2, v.z);
    atomicAdd(ap + 3, v.w);
}

__global__ __launch_bounds__(256, 1) void fused_gemm(
        const float* __restrict__ agg, const float* __restrict__ x,
        const float* __restrict__ Wrel, const float* __restrict__ brel,
        const float* __restrict__ Wroot, float* __restrict__ out,
        int nChunks) {
    __shared__ float W2t[256][128];
    __shared__ float rows[16][256];
    int tid = threadIdx.x;
    for (int idx = tid; idx < 256 * 128; idx += 256) {
        int k = idx >> 7, m = idx & 127;
        W2t[k][m] = (k < 128) ? Wrel[m * 128 + k] : Wroot[m * 128 + (k - 128)];
    }
    __syncthreads();
    int mq = tid & 31, rg = tid >> 5, m4 = mq * 4;
    for (int chunk = blockIdx.x; chunk < nChunks; chunk += gridDim.x) {
        size_t row0 = (size_t)chunk * 16;
        __syncthreads();
        for (int j = 0; j < 4; ++j) {
            int i = (tid + j * 256) * 4;
            int r = i >> 8, c = i & 255;
            float4 v;
            if (c < 128) v = *(const float4*)&agg[(row0 + r) * D + c];
            else         v = *(const float4*)&x[(row0 + r) * D + (c - 128)];
            *(float4*)&rows[r][c] = v;
        }
        __syncthreads();
        float4 acc0 = make_float4(0, 0, 0, 0), acc1 = make_float4(0, 0, 0, 0);
#pragma unroll 8
        for (int k = 0; k < 256; ++k) {
            float4 wv = *(const float4*)&W2t[k][m4];
            float A0 = rows[rg][k], A1 = rows[rg + 8][k];
            acc0.x = fmaf(A0, wv.x, acc0.x); acc0.y = fmaf(A0, wv.y, acc0.y);
            acc0.z = fmaf(A0, wv.z, acc0.z); acc0.w = fmaf(A0, wv.w, acc0.w);
            acc1.x = fmaf(A1, wv.x, acc1.x); acc1.y = fmaf(A1, wv.y, acc1.y);
            acc1.z = fmaf(A1, wv.z, acc1.z); acc1.w = fmaf(A1, wv.w, acc1.w);
        }
        float4 b = *(const float4*)&brel[m4];
        *(float4*)&out[(row0 + rg) * D + m4] =
            make_float4(acc0.x + b.x, acc0.y + b.y, acc0.z + b.z, acc0.w + b.w);
        *(float4*)&out[(row0 + rg + 8) * D + m4] =
            make_float4(acc1.x + b.x, acc1.y + b.y, acc1.z + b.z, acc1.w + b.w);
    }
}

extern "C" void kernel_launch(void* const* d_in, const int* in_sizes, int n_in,
                              void* d_out, int out_size, void* d_ws, size_t ws_size,
                              hipStream_t stream) {
    const float* x     = (const float*)d_in[0];
    const int*   ei    = (const int*)d_in[1];
    const float* Wrel  = (const float*)d_in[2];
    const float* brel  = (const float*)d_in[3];
    const float* Wroot = (const float*)d_in[4];
    float* out = (float*)d_out;

    const size_t amatBytes = (size_t)N_NODES * K2 * sizeof(unsigned short); // 51.2 MB
    const size_t offBytes  = (size_t)(N_NODES + 1) * sizeof(int);
    const size_t curBytes  = (size_t)N_NODES * sizeof(int);
    const size_t srcBytes  = (size_t)N_EDGES * sizeof(int);
    const size_t cntBytes  = (size_t)N_NODES * sizeof(int);
    const size_t blkBytes  = (size_t)NBLK * sizeof(int);
    const size_t wfBytes   = (size_t)4096 * 8 * sizeof(unsigned short);     // 64 KB
    auto align16 = [](size_t v) { return (v + 15) & ~(size_t)15; };

    size_t o_amat = 0;
    size_t o_off  = align16(o_amat + amatBytes);
    size_t o_cur  = align16(o_off + offBytes);
    size_t o_src  = align16(o_cur + curBytes);
    size_t o_cnt  = align16(o_src + srcBytes);
    size_t o_bs   = align16(o_cnt + cntBytes);
    size_t o_bo   = align16(o_bs + blkBytes);
    size_t o_wf   = align16(o_bo + blkBytes);
    size_t total  = o_wf + wfBytes;

    if (ws_size >= total) {
        char* ws = (char*)d_ws;
        unsigned short* Amat  = (unsigned short*)(ws + o_amat);
        int*   offsets   = (int*)(ws + o_off);
        int*   cursor    = (int*)(ws + o_cur);
        int*   srcSorted = (int*)(ws + o_src);
        int*   counts    = (int*)(ws + o_cnt);
        int*   blockSums = (int*)(ws + o_bs);
        int*   blockOff  = (int*)(ws + o_bo);
        unsigned short* Wfrag = (unsigned short*)(ws + o_wf);

        hipMemsetAsync(counts, 0, cntBytes, stream);
        hist_kernel<<<(N_EDGES + 255) / 256, 256, 0, stream>>>(ei, counts);
        wprep_kernel<<<16, 256, 0, stream>>>(Wrel, Wroot, Wfrag);
        convert_x_kernel<<<(N_NODES * 16 + 255) / 256, 256, 0, stream>>>(x, Amat);
        tile_sum_kernel<<<NBLK, SCAN_TILE, 0, stream>>>(counts, blockSums);
        scan_blocks_kernel<<<1, 128, 0, stream>>>(blockSums, blockOff);
        scan_tile_kernel<<<NBLK, SCAN_TILE, 0, stream>>>(counts, blockOff, offsets, cursor);
        scatter_idx_kernel<<<(N_EDGES + 255) / 256, 256, 0, stream>>>(ei, cursor, srcSorted);
        seg_sum_kernel<<<(N_NODES * 64 + 255) / 256, 256, 0, stream>>>(x, offsets, srcSorted, Amat);
        gemm_mfma<<<(N_NODES + 127) / 128, 256, 0, stream>>>(Amat, Wfrag, brel, out);
    } else {
        // Fallback: atomic scatter + fp32 GEMM.
        float* agg = (ws_size >= (size_t)N_NODES * D * sizeof(float)) ? (float*)d_ws : out;
        hipMemsetAsync(agg, 0, (size_t)N_NODES * D * sizeof(float), stream);
        scatter_kernel<<<(N_EDGES * 32 + 255) / 256, 256, 0, stream>>>(x, ei, agg);
        fused_gemm<<<256, 256, 0, stream>>>(agg, x, Wrel, brel, Wroot, out,
                                            N_NODES / 16);
    }
}